// Round 4
// baseline (3763.297 us; speedup 1.0000x reference)
//
#include <hip/hip_runtime.h>

// BaseRNN B=64,S=512,H=E=512,L=2 — persistent kernel, R14.
// R12/R13 theory (untested: rounds 2-3 died with no counters): the 4-hop sync
// chain (drain->flag->detect->load) costs ~1us/hop at agent scope (MALL). The
// sync group (32 WGs of dom = wg&7) lands on ONE XCD under round-robin
// blockIdx->XCD; sc0 (SE-scope, XCD-L2) hops are ~5x cheaper. Probe-gated.
// R14 hardening vs R13 (two identical harness deaths -> de-risk):
//  - XCC_ID via __builtin_amdgcn_s_getreg (no asm-syntax risk)
//  - tied-operand waitcnt asm -> plain WAIT_VM0 (ds_writes are memory ops,
//    ordered by the "memory" clobber; rule-18 hazard is register-only users)
//  - sc0 proof -> 4-round bounded ping-pong: cross-XCD spurious pass would
//    need repeated writeback luck AGAINST the re-caching dynamic (each stale
//    poll re-fills consumer L2 clean). Same-XCD completes deterministically.
//    On budget exhaustion the dom votes slow -> exact R10 sc1 protocol.
// Ring 64 slots: live window stays L2-resident (2MB/XCD).

#define BATCH 64
#define SEQ   512
#define HID   512
#define NTHR  256
#define CB    8
#define ROWS  32
#define SLOT  (BATCH * HID)     // floats per ring slot (128KB)

typedef unsigned int u32;
typedef unsigned long long u64;

__device__ __forceinline__ float dot4(const float4 a, const float4 b) {
  return a.x * b.x + a.y * b.y + a.z * b.z + a.w * b.w;
}
__device__ __forceinline__ u64 ldu(const double* p) {      // sc1 8B load
  const double d = __hip_atomic_load(p, __ATOMIC_RELAXED, __HIP_MEMORY_SCOPE_AGENT);
  return __builtin_bit_cast(u64, d);
}
__device__ __forceinline__ void st2(double* p, float2 v) { // sc1 8B store
  __hip_atomic_store(p, __builtin_bit_cast(double, v),
                     __ATOMIC_RELAXED, __HIP_MEMORY_SCOPE_AGENT);
}
// ---- SE-scope (XCD-L2 venue) ops: sc0 = bypass L1, service from L2 ----
__device__ __forceinline__ u64 ld8_sc0(const double* p) {  // issue only, no wait
  u64 r;
  asm volatile("global_load_dwordx2 %0, %1, off sc0" : "=v"(r) : "v"(p) : "memory");
  return r;
}
__device__ __forceinline__ void st8_sc0(double* p, u64 v) {
  asm volatile("global_store_dwordx2 %0, %1, off sc0" :: "v"(p), "v"(v) : "memory");
}
__device__ __forceinline__ u32 ld_flag_sc0(const u32* p) {
  u32 r;
  asm volatile("global_load_dword %0, %1, off sc0\n\ts_waitcnt vmcnt(0)"
               : "=v"(r) : "v"(p) : "memory");
  return r;
}
__device__ __forceinline__ void st_flag_sc0(u32* p, u32 v) {
  asm volatile("global_store_dword %0, %1, off sc0" :: "v"(p), "v"(v) : "memory");
}
__device__ __forceinline__ float tanh_fast(float x) {
  const float a = fabsf(x);
  const float e = __expf(-2.0f * a);
  const float t = (1.0f - e) * __builtin_amdgcn_rcpf(1.0f + e);
  return copysignf(t, x);
}
#define WAIT_VM0() asm volatile("s_waitcnt vmcnt(0)" ::: "memory")
// s_getreg imm: id | (offset<<6) | ((size-1)<<11); HW_REG_XCC_ID=20, 32 bits
#define GETREG_XCC ((20) | (0 << 6) | (31 << 11))

#define RSTEP(D, N)                                                   \
  {                                                                   \
    const bool hi = (lane & (D)) != 0;                                \
    _Pragma("unroll")                                                 \
    for (int a = 0; a < (N); ++a) {                                   \
      const float keep = hi ? v[a + (N)] : v[a];                      \
      const float send = hi ? v[a] : v[a + (N)];                      \
      v[a] = keep + __shfl_xor(send, (D));                            \
    }                                                                 \
  }

__global__ __launch_bounds__(NTHR, 1) void rnn_persistent(
    const int* __restrict__ x, const int* __restrict__ lengths,
    const float* __restrict__ emb,
    const float* __restrict__ W_ih, const float* __restrict__ W_hh,
    const float* __restrict__ b_ih, const float* __restrict__ b_hh,
    float* __restrict__ out,
    float* h0r, float* h1r, u32* F, int ring)
{
  __shared__ __align__(16) float Xa[CB][HID];        // 16KB
  __shared__ __align__(16) float Xb[CB][HID];        // 16KB
  __shared__ __align__(16) float Xpart[CB][ROWS][4]; // 4KB
  __shared__ int Lens[CB];
  __shared__ int FastSh;

  const int wg    = blockIdx.x;
  const int tid   = threadIdx.x;
  const int dom   = wg & 7;
  const int q     = wg >> 3;
  const int layer = q >> 4;
  const int rg    = q & 15;
  const int bbase = dom * CB;
  const int jbase = rg * ROWS;
  const int tj    = tid >> 6;
  const int lane  = tid & 63;

  // flags: entry (dom,layer,rg) on its own 128B line; value = #slots written
  u32* Fown = F + ((dom * 2 + layer) * 16 + rg) * 32;
  u32* F0   = F + ((dom * 2 + 0) * 16) * 32;   // + i*32
  u32* F1   = F + ((dom * 2 + 1) * 16) * 32;
  // probe area (zeroed each call)
  u32* Tok = F + 8192 + dom * 32;   // sc1 tokens: xcc_id + 2
  u32* Prf = F + 8448 + dom * 32;   // sc0 ping-pong round counters
  u32* Vot = F + 8704 + dom * 32;   // votes: 1=no, 2=yes
  const int slot32 = layer * 16 + rg;

  // ---- probe step 1: publish token + proof round 1 EARLY ----
  const int xcc = (int)(__builtin_amdgcn_s_getreg(GETREG_XCC) & 0xf);
  if (tid == 0) {
    __hip_atomic_store(&Tok[slot32], (u32)(xcc + 2),
                       __ATOMIC_RELAXED, __HIP_MEMORY_SCOPE_AGENT);
    st_flag_sc0(&Prf[slot32], 1u);
  }

  // ---- weights in registers: 8 j x (2 float4 k) x 2 mats = 128 VGPRs ----
  float4 wa[2][8], wb[2][8];
  {
    const float* WA = W_ih + layer * (HID * HID);
    const float* WB = W_hh + layer * (HID * HID);
    #pragma unroll
    for (int ji = 0; ji < 8; ++ji) {
      const int j = jbase + tj * 8 + ji;
      #pragma unroll
      for (int i = 0; i < 2; ++i) {
        const int k = i * 256 + 4 * lane;
        wa[i][ji] = *(const float4*)&WA[j * HID + k];
        wb[i][ji] = *(const float4*)&WB[j * HID + k];
      }
    }
  }
  if (tid < CB) Lens[tid] = lengths[bbase + tid];
  __syncthreads();
  int maxlen = Lens[0];
  #pragma unroll
  for (int i = 1; i < CB; ++i) maxlen = max(maxlen, Lens[i]);
  const int P     = maxlen;                       // 1..512
  const int pl0   = (P < SEQ) ? P : (SEQ - 1);    // l0's last active phase
  const int plast = layer ? P : pl0;
  int lm[4];                                      // group liveness bounds
  #pragma unroll
  for (int g = 0; g < 4; ++g) lm[g] = max(Lens[2 * g], Lens[2 * g + 1]);

  float4 bias4 = make_float4(0.f, 0.f, 0.f, 0.f);
  if (tid < 64) {
    const int jq = jbase + (tid & 7) * 4;
    bias4.x = b_ih[layer * HID + jq + 0] + b_hh[layer * HID + jq + 0];
    bias4.y = b_ih[layer * HID + jq + 1] + b_hh[layer * HID + jq + 1];
    bias4.z = b_ih[layer * HID + jq + 2] + b_hh[layer * HID + jq + 2];
    bias4.w = b_ih[layer * HID + jq + 3] + b_hh[layer * HID + jq + 3];
  }

  // ---- initial emb prefetch (t=0, l0) ----
  float4 pf[4];
  if (layer == 0) {
    #pragma unroll
    for (int i = 0; i < 4; ++i) {
      const int u = tid + NTHR * i;
      const int r = u >> 7, c = (u & 127) * 4;
      const int tok = x[(bbase + r) * SEQ];
      pf[i] = *(const float4*)&emb[(size_t)tok * HID + c];
    }
  }

  // ---- probe steps 2-4: decide venue (group-uniform, hang-free) ----
  if (tid < 64) {
    // 2a) sc1 token gather — every WG stores unconditionally at entry and all
    //     256 WGs are co-resident (grid == CU count) -> provably completes.
    u32 tok = 0;
    while (true) {
      if (lane < 32 && tok == 0)
        tok = __hip_atomic_load(&Tok[lane], __ATOMIC_RELAXED,
                                __HIP_MEMORY_SCOPE_AGENT);
      if (__ballot(lane >= 32 || tok != 0) == ~0ull) break;
    }
    const u32 t0 = __shfl(tok, 0);
    const bool samex = (__ballot(lane >= 32 || tok == t0) == ~0ull);
    // 2b) 4-round sc0 ping-pong proof — bounded budget; publish round r+1
    //     only after seeing ALL peers at >= r. Cross-XCD cannot sustain this.
    bool ok = false;
    if (samex) {
      int budget = 6000;
      bool fail = false;
      for (int r = 1; r <= 4 && !fail; ++r) {
        bool seen = (lane >= 32);
        while (true) {
          if (!seen) seen = (ld_flag_sc0(&Prf[lane]) >= (u32)r);
          if (__ballot(seen) == ~0ull) break;
          if (--budget <= 0) { fail = true; break; }
        }
        if (!fail && r < 4 && lane == 0)
          st_flag_sc0(&Prf[slot32], (u32)(r + 1));
      }
      ok = !fail;
    }
    // 3) vote (sc1) — every WG votes unconditionally; 4) gather all 32 votes.
    //    All WGs see the same once-written values -> decision group-uniform.
    if (tid == 0)
      __hip_atomic_store(&Vot[slot32], ok ? 2u : 1u,
                         __ATOMIC_RELAXED, __HIP_MEMORY_SCOPE_AGENT);
    u32 vv = 0;
    while (true) {
      if (lane < 32 && vv == 0)
        vv = __hip_atomic_load(&Vot[lane], __ATOMIC_RELAXED,
                               __HIP_MEMORY_SCOPE_AGENT);
      if (__ballot(lane >= 32 || vv != 0) == ~0ull) break;
    }
    const bool allf = (__ballot(lane >= 32 || vv == 2) == ~0ull);
    if (tid == 0) FastSh = allf ? 1 : 0;
  }
  __syncthreads();
  const bool fast = (FastSh != 0);

  int cur = 0, prev = ring - 1;   // p % ring, (p-1) % ring

  for (int p = 0; p <= P; ++p) {
    const bool active = layer ? (p >= 1) : (p < SEQ);
    const int  wr0    = (cur + 1 == ring) ? 0 : (cur + 1);

    if (active) {
      const int t = layer ? (p - 1) : p;

      // ---- stage: ring loads -> LDS (venue per probe) ----
      if (layer == 0) {
        const double* src = (const double*)(h0r) + (size_t)cur * (SLOT / 2);
        u64 tv[8];
        if (fast) {
          #pragma unroll
          for (int i = 0; i < 8; ++i) {
            const int u = tid + NTHR * i;
            tv[i] = ld8_sc0(&src[(size_t)(bbase + (u >> 8)) * 256 + (u & 255)]);
          }
          WAIT_VM0();   // ds_writes below are memory ops: ordered after this
        } else {
          #pragma unroll
          for (int i = 0; i < 8; ++i) {
            const int u = tid + NTHR * i;
            tv[i] = ldu(&src[(size_t)(bbase + (u >> 8)) * 256 + (u & 255)]);
          }
        }
        #pragma unroll
        for (int i = 0; i < 8; ++i) {
          const int u = tid + NTHR * i;
          *(float2*)&Xb[u >> 8][(u & 255) * 2] = __builtin_bit_cast(float2, tv[i]);
        }
        #pragma unroll
        for (int i = 0; i < 4; ++i) {
          const int u = tid + NTHR * i;
          *(float4*)&Xa[u >> 7][(u & 127) * 4] = pf[i];
        }
      } else {
        const double* srcB = (const double*)(h1r) + (size_t)prev * (SLOT / 2);
        const double* srcA = (const double*)(h0r) + (size_t)cur  * (SLOT / 2);
        u64 tb[8], ta[8];
        if (fast) {
          #pragma unroll                       // critical (h1 self-chain) first
          for (int i = 0; i < 8; ++i) {
            const int u = tid + NTHR * i;
            tb[i] = ld8_sc0(&srcB[(size_t)(bbase + (u >> 8)) * 256 + (u & 255)]);
          }
          #pragma unroll
          for (int i = 0; i < 8; ++i) {
            const int u = tid + NTHR * i;
            ta[i] = ld8_sc0(&srcA[(size_t)(bbase + (u >> 8)) * 256 + (u & 255)]);
          }
          WAIT_VM0();
        } else {
          #pragma unroll
          for (int i = 0; i < 8; ++i) {
            const int u = tid + NTHR * i;
            tb[i] = ldu(&srcB[(size_t)(bbase + (u >> 8)) * 256 + (u & 255)]);
          }
          #pragma unroll
          for (int i = 0; i < 8; ++i) {
            const int u = tid + NTHR * i;
            ta[i] = ldu(&srcA[(size_t)(bbase + (u >> 8)) * 256 + (u & 255)]);
          }
        }
        #pragma unroll
        for (int i = 0; i < 8; ++i) {
          const int u = tid + NTHR * i;
          *(float2*)&Xb[u >> 8][(u & 255) * 2] = __builtin_bit_cast(float2, tb[i]);
          *(float2*)&Xa[u >> 8][(u & 255) * 2] = __builtin_bit_cast(float2, ta[i]);
        }
      }
      __syncthreads();

      // ---- compute: 4 groups, unroll 2; skip fully-frozen groups ----
      #pragma unroll 2
      for (int g = 0; g < 4; ++g) {
        if (t >= lm[g]) continue;            // wave-uniform (Lens shared)
        float v[16];
        #pragma unroll
        for (int o = 0; o < 16; ++o) v[o] = 0.f;
        #pragma unroll
        for (int bi = 0; bi < 2; ++bi) {
          const int b = g * 2 + bi;
          const float4 xa0 = *(const float4*)&Xa[b][4 * lane];
          const float4 xa1 = *(const float4*)&Xa[b][256 + 4 * lane];
          const float4 xb0 = *(const float4*)&Xb[b][4 * lane];
          const float4 xb1 = *(const float4*)&Xb[b][256 + 4 * lane];
          #pragma unroll
          for (int ji = 0; ji < 8; ++ji) {
            v[bi * 8 + ji] += dot4(wa[0][ji], xa0) + dot4(wa[1][ji], xa1)
                            + dot4(wb[0][ji], xb0) + dot4(wb[1][ji], xb1);
          }
        }
        RSTEP(32, 8)
        RSTEP(16, 4)
        RSTEP(8, 2)
        RSTEP(4, 1)
        const int b_o = g * 2 + (lane >> 5);
        const int j_o = tj * 8 + ((lane >> 2) & 7);
        Xpart[b_o][j_o][lane & 3] = v[0];
      }
      __syncthreads();

      // ---- finalize: sum partials, fast tanh, mask, ring store ----
      if (tid < 64) {
        const int b = tid >> 3, jq = (tid & 7) * 4;
        const float4 hb = *(const float4*)&Xb[b][jbase + jq];
        const bool live = (t < Lens[b]);
        float4 r = hb;
        if (live) {
          const float4 p0 = *(const float4*)&Xpart[b][jq + 0][0];
          const float4 p1 = *(const float4*)&Xpart[b][jq + 1][0];
          const float4 p2 = *(const float4*)&Xpart[b][jq + 2][0];
          const float4 p3 = *(const float4*)&Xpart[b][jq + 3][0];
          r.x = tanh_fast(p0.x + p0.y + p0.z + p0.w + bias4.x);
          r.y = tanh_fast(p1.x + p1.y + p1.z + p1.w + bias4.y);
          r.z = tanh_fast(p2.x + p2.y + p2.z + p2.w + bias4.z);
          r.w = tanh_fast(p3.x + p3.y + p3.z + p3.w + bias4.w);
        }
        double* dst = layer ? ((double*)h1r + (size_t)cur * (SLOT / 2))
                            : ((double*)h0r + (size_t)wr0 * (SLOT / 2));
        const size_t di = (size_t)(bbase + b) * 256 + ((jbase + jq) >> 1);
        if (fast) {
          st8_sc0(&dst[di],     __builtin_bit_cast(u64, make_float2(r.x, r.y)));
          st8_sc0(&dst[di + 1], __builtin_bit_cast(u64, make_float2(r.z, r.w)));
        } else {
          st2(&dst[di],     make_float2(r.x, r.y));
          st2(&dst[di + 1], make_float2(r.z, r.w));
        }
        if (p == plast) {   // fused epilogue: own tile = own output
          if (layer == 0) {
            *(float4*)&out[32768 + (size_t)(bbase + b) * 1024 + jbase + jq] = r;
          } else {
            *(float4*)&out[(size_t)(bbase + b) * 512 + jbase + jq] = r;
            *(float4*)&out[32768 + (size_t)(bbase + b) * 1024 + 512 + jbase + jq] = r;
          }
        }
      }
    }

    // ---- exchange: drain -> flag store -> prefetch -> parallel detect ----
    WAIT_VM0();
    __syncthreads();
    if (tid == 0 && active) {  // l0 publishes p+1 slots, l1 publishes p
      const u32 fv = (u32)(layer ? p : (p + 1));
      if (fast) st_flag_sc0(Fown, fv);
      else __hip_atomic_store(Fown, fv, __ATOMIC_RELAXED, __HIP_MEMORY_SCOPE_AGENT);
    }
    const int np = p + 1;
    if (layer == 0 && np <= plast) {
      #pragma unroll
      for (int i = 0; i < 4; ++i) {
        const int u = tid + NTHR * i;
        const int r = u >> 7, c = (u & 127) * 4;
        const int tok = x[(bbase + r) * SEQ + np];
        pf[i] = *(const float4*)&emb[(size_t)tok * HID + c];
      }
    }
    if (np <= P) {
      if (tid < 64) {
        u32* fp  = Fown;            // dummy for idle lanes (always valid)
        u32  tgt = 0;
        bool idle = true;
        if (lane < 16) { fp = F0 + lane * 32; tgt = (u32)np; idle = false; }
        else if (lane < 32) {
          if (layer) { fp = F1 + (lane - 16) * 32; tgt = (u32)(np - 1); idle = false; }
          else {
            const int th = np + 1 - ring;   // small-ring WAR throttle
            if (th > 0) { fp = F1 + (lane - 16) * 32; tgt = (u32)th; idle = false; }
          }
        }
        while (true) {
          const u32 vv = fast ? ld_flag_sc0(fp)
                              : __hip_atomic_load(fp, __ATOMIC_RELAXED,
                                                  __HIP_MEMORY_SCOPE_AGENT);
          const bool ok = idle || (vv >= tgt);
          if (__ballot(ok) == ~0ull) break;
        }
      }
      __syncthreads();
    }
    prev = cur; cur = wr0;
  }
}

extern "C" void kernel_launch(void* const* d_in, const int* in_sizes, int n_in,
                              void* d_out, int out_size, void* d_ws, size_t ws_size,
                              hipStream_t stream) {
  (void)in_sizes; (void)n_in; (void)out_size;
  const int*   x       = (const int*)d_in[0];
  const int*   lengths = (const int*)d_in[1];
  const float* emb     = (const float*)d_in[2];
  const float* W_ih    = (const float*)d_in[3];
  const float* W_hh    = (const float*)d_in[4];
  const float* b_ih    = (const float*)d_in[5];
  const float* b_hh    = (const float*)d_in[6];
  float* out = (float*)d_out;

  const size_t slotB  = (size_t)SLOT * sizeof(float);           // 128KB
  const size_t need64 = 2 * (size_t)64 * slotB + 65536;         // ~16.8MB
  const int ring = (ws_size >= need64) ? 64 : 17;               // 17: throttled

  float* h0r = (float*)d_ws;
  float* h1r = h0r + (size_t)ring * SLOT;
  u32*   F   = (u32*)(h1r + (size_t)ring * SLOT);

  // zero slot 0 of each ring (h(-1)=0) + flag/probe page; ws re-poisoned
  // between calls, inter-kernel coherence flushes/invalidates L2s.
  hipMemsetAsync(h0r, 0, slotB, stream);
  hipMemsetAsync(h1r, 0, slotB, stream);
  hipMemsetAsync(F, 0, 65536, stream);

  hipLaunchKernelGGL(rnn_persistent, dim3(256), dim3(NTHR), 0, stream,
                     x, lengths, emb, W_ih, W_hh, b_ih, b_hh, out,
                     h0r, h1r, F, ring);
}

// Round 5
// 2918.625 us; speedup vs baseline: 1.2894x; 1.2894x over previous
//
#include <hip/hip_runtime.h>

// BaseRNN B=64,S=512,H=E=512,L=2 — persistent kernel, R15.
// R11 (NP data-poll): 3240 — REGRESSED, poll congestion at MALL.
// R14 (sc0 venue probe): 3763 — REGRESSED, VGPR 128->108 = probe control flow
//   wrecked regalloc (weights need 128 VGPRs); WRITE_SIZE unchanged => no
//   counter evidence the sc0 path engaged as theorized. Both bets closed.
// R15 = exact R10 protocol (this session never benched it) + 3 additive,
// regalloc-neutral micro-opts:
//  (1) latched poll: a lane stops re-loading once its peer flag passed —
//      cuts steady-state MALL poll traffic to stragglers only.
//  (2) s_sleep(1) backoff on failed ballot (fabric pressure relief).
//  (3) early flag publish: wave0 publishes right after ITS vmcnt(0) drain,
//      before the barrier join (ring data is written+drained by wave0 only).
// Everything else — ring 513 (L3-resident, no WAR throttle), sc1 flags,
// 16 WG x 256 thr per dom-layer, fused epilogue, emb prefetch — is R10.

#define BATCH 64
#define SEQ   512
#define HID   512
#define NTHR  256
#define CB    8
#define ROWS  32
#define SLOT  (BATCH * HID)     // floats per ring slot (128KB)

typedef unsigned int u32;

__device__ __forceinline__ float dot4(const float4 a, const float4 b) {
  return a.x * b.x + a.y * b.y + a.z * b.z + a.w * b.w;
}
__device__ __forceinline__ float2 ld2(const double* p) {   // sc1 8B load
  const double d = __hip_atomic_load(p, __ATOMIC_RELAXED, __HIP_MEMORY_SCOPE_AGENT);
  return __builtin_bit_cast(float2, d);
}
__device__ __forceinline__ void st2(double* p, float2 v) { // sc1 8B store
  __hip_atomic_store(p, __builtin_bit_cast(double, v),
                     __ATOMIC_RELAXED, __HIP_MEMORY_SCOPE_AGENT);
}
__device__ __forceinline__ float tanh_fast(float x) {
  const float a = fabsf(x);
  const float e = __expf(-2.0f * a);
  const float t = (1.0f - e) * __builtin_amdgcn_rcpf(1.0f + e);
  return copysignf(t, x);
}
#define WAIT_VM0() asm volatile("s_waitcnt vmcnt(0)" ::: "memory")

#define RSTEP(D, N)                                                   \
  {                                                                   \
    const bool hi = (lane & (D)) != 0;                                \
    _Pragma("unroll")                                                 \
    for (int a = 0; a < (N); ++a) {                                   \
      const float keep = hi ? v[a + (N)] : v[a];                      \
      const float send = hi ? v[a] : v[a + (N)];                      \
      v[a] = keep + __shfl_xor(send, (D));                            \
    }                                                                 \
  }

__global__ __launch_bounds__(NTHR, 1) void rnn_persistent(
    const int* __restrict__ x, const int* __restrict__ lengths,
    const float* __restrict__ emb,
    const float* __restrict__ W_ih, const float* __restrict__ W_hh,
    const float* __restrict__ b_ih, const float* __restrict__ b_hh,
    float* __restrict__ out,
    float* h0r, float* h1r, u32* F, int ring)
{
  __shared__ __align__(16) float Xa[CB][HID];        // 16KB
  __shared__ __align__(16) float Xb[CB][HID];        // 16KB
  __shared__ __align__(16) float Xpart[CB][ROWS][4]; // 4KB
  __shared__ int Lens[CB];

  const int wg    = blockIdx.x;
  const int tid   = threadIdx.x;
  const int dom   = wg & 7;
  const int q     = wg >> 3;
  const int layer = q >> 4;
  const int rg    = q & 15;
  const int bbase = dom * CB;
  const int jbase = rg * ROWS;
  const int tj    = tid >> 6;
  const int lane  = tid & 63;

  // flags: entry (dom,layer,rg) on its own 128B line; value = #slots written
  u32* Fown = F + ((dom * 2 + layer) * 16 + rg) * 32;
  u32* F0   = F + ((dom * 2 + 0) * 16) * 32;   // + i*32
  u32* F1   = F + ((dom * 2 + 1) * 16) * 32;

  // ---- weights in registers: 8 j x (2 float4 k) x 2 mats = 128 VGPRs ----
  float4 wa[2][8], wb[2][8];
  {
    const float* WA = W_ih + layer * (HID * HID);
    const float* WB = W_hh + layer * (HID * HID);
    #pragma unroll
    for (int ji = 0; ji < 8; ++ji) {
      const int j = jbase + tj * 8 + ji;
      #pragma unroll
      for (int i = 0; i < 2; ++i) {
        const int k = i * 256 + 4 * lane;
        wa[i][ji] = *(const float4*)&WA[j * HID + k];
        wb[i][ji] = *(const float4*)&WB[j * HID + k];
      }
    }
  }
  if (tid < CB) Lens[tid] = lengths[bbase + tid];
  __syncthreads();
  int maxlen = Lens[0];
  #pragma unroll
  for (int i = 1; i < CB; ++i) maxlen = max(maxlen, Lens[i]);
  const int P     = maxlen;                       // 1..512
  const int pl0   = (P < SEQ) ? P : (SEQ - 1);    // l0's last active phase
  const int plast = layer ? P : pl0;
  int lm[4];                                      // group liveness bounds
  #pragma unroll
  for (int g = 0; g < 4; ++g) lm[g] = max(Lens[2 * g], Lens[2 * g + 1]);

  float4 bias4 = make_float4(0.f, 0.f, 0.f, 0.f);
  if (tid < 64) {
    const int jq = jbase + (tid & 7) * 4;
    bias4.x = b_ih[layer * HID + jq + 0] + b_hh[layer * HID + jq + 0];
    bias4.y = b_ih[layer * HID + jq + 1] + b_hh[layer * HID + jq + 1];
    bias4.z = b_ih[layer * HID + jq + 2] + b_hh[layer * HID + jq + 2];
    bias4.w = b_ih[layer * HID + jq + 3] + b_hh[layer * HID + jq + 3];
  }

  // ---- initial emb prefetch (t=0, l0) ----
  float4 pf[4];
  if (layer == 0) {
    #pragma unroll
    for (int i = 0; i < 4; ++i) {
      const int u = tid + NTHR * i;
      const int r = u >> 7, c = (u & 127) * 4;
      const int tok = x[(bbase + r) * SEQ];
      pf[i] = *(const float4*)&emb[(size_t)tok * HID + c];
    }
  }

  int cur = 0, prev = ring - 1;   // p % ring, (p-1) % ring

  for (int p = 0; p <= P; ++p) {
    const bool active = layer ? (p >= 1) : (p < SEQ);
    const int  wr0    = (cur + 1 == ring) ? 0 : (cur + 1);

    if (active) {
      const int t = layer ? (p - 1) : p;

      // ---- stage: sc1 ring loads -> LDS ----
      if (layer == 0) {
        const double* src = (const double*)(h0r) + (size_t)cur * (SLOT / 2);
        float2 tv[8];
        #pragma unroll
        for (int i = 0; i < 8; ++i) {
          const int u = tid + NTHR * i;
          tv[i] = ld2(&src[(size_t)(bbase + (u >> 8)) * 256 + (u & 255)]);
        }
        #pragma unroll
        for (int i = 0; i < 8; ++i) {
          const int u = tid + NTHR * i;
          *(float2*)&Xb[u >> 8][(u & 255) * 2] = tv[i];
        }
        #pragma unroll
        for (int i = 0; i < 4; ++i) {
          const int u = tid + NTHR * i;
          *(float4*)&Xa[u >> 7][(u & 127) * 4] = pf[i];
        }
      } else {
        const double* srcB = (const double*)(h1r) + (size_t)prev * (SLOT / 2);
        const double* srcA = (const double*)(h0r) + (size_t)cur  * (SLOT / 2);
        float2 tb[8], ta[8];
        #pragma unroll
        for (int i = 0; i < 8; ++i) {
          const int u = tid + NTHR * i;
          tb[i] = ld2(&srcB[(size_t)(bbase + (u >> 8)) * 256 + (u & 255)]);
        }
        #pragma unroll
        for (int i = 0; i < 8; ++i) {
          const int u = tid + NTHR * i;
          ta[i] = ld2(&srcA[(size_t)(bbase + (u >> 8)) * 256 + (u & 255)]);
        }
        #pragma unroll
        for (int i = 0; i < 8; ++i) {
          const int u = tid + NTHR * i;
          *(float2*)&Xb[u >> 8][(u & 255) * 2] = tb[i];
          *(float2*)&Xa[u >> 8][(u & 255) * 2] = ta[i];
        }
      }
      __syncthreads();

      // ---- compute: 4 groups, unroll 2; skip fully-frozen groups ----
      #pragma unroll 2
      for (int g = 0; g < 4; ++g) {
        if (t >= lm[g]) continue;            // wave-uniform (Lens shared)
        float v[16];
        #pragma unroll
        for (int o = 0; o < 16; ++o) v[o] = 0.f;
        #pragma unroll
        for (int bi = 0; bi < 2; ++bi) {
          const int b = g * 2 + bi;
          const float4 xa0 = *(const float4*)&Xa[b][4 * lane];
          const float4 xa1 = *(const float4*)&Xa[b][256 + 4 * lane];
          const float4 xb0 = *(const float4*)&Xb[b][4 * lane];
          const float4 xb1 = *(const float4*)&Xb[b][256 + 4 * lane];
          #pragma unroll
          for (int ji = 0; ji < 8; ++ji) {
            v[bi * 8 + ji] += dot4(wa[0][ji], xa0) + dot4(wa[1][ji], xa1)
                            + dot4(wb[0][ji], xb0) + dot4(wb[1][ji], xb1);
          }
        }
        RSTEP(32, 8)
        RSTEP(16, 4)
        RSTEP(8, 2)
        RSTEP(4, 1)
        const int b_o = g * 2 + (lane >> 5);
        const int j_o = tj * 8 + ((lane >> 2) & 7);
        Xpart[b_o][j_o][lane & 3] = v[0];
      }
      __syncthreads();

      // ---- finalize: sum partials, fast tanh, mask, sc1 ring store ----
      if (tid < 64) {
        const int b = tid >> 3, jq = (tid & 7) * 4;
        const float4 hb = *(const float4*)&Xb[b][jbase + jq];
        const bool live = (t < Lens[b]);
        float4 r = hb;
        if (live) {
          const float4 p0 = *(const float4*)&Xpart[b][jq + 0][0];
          const float4 p1 = *(const float4*)&Xpart[b][jq + 1][0];
          const float4 p2 = *(const float4*)&Xpart[b][jq + 2][0];
          const float4 p3 = *(const float4*)&Xpart[b][jq + 3][0];
          r.x = tanh_fast(p0.x + p0.y + p0.z + p0.w + bias4.x);
          r.y = tanh_fast(p1.x + p1.y + p1.z + p1.w + bias4.y);
          r.z = tanh_fast(p2.x + p2.y + p2.z + p2.w + bias4.z);
          r.w = tanh_fast(p3.x + p3.y + p3.z + p3.w + bias4.w);
        }
        double* dst = layer ? ((double*)h1r + (size_t)cur * (SLOT / 2))
                            : ((double*)h0r + (size_t)wr0 * (SLOT / 2));
        const size_t di = (size_t)(bbase + b) * 256 + ((jbase + jq) >> 1);
        st2(&dst[di],     make_float2(r.x, r.y));
        st2(&dst[di + 1], make_float2(r.z, r.w));
        if (p == plast) {   // fused epilogue: own tile = own output
          if (layer == 0) {
            *(float4*)&out[32768 + (size_t)(bbase + b) * 1024 + jbase + jq] = r;
          } else {
            *(float4*)&out[(size_t)(bbase + b) * 512 + jbase + jq] = r;
            *(float4*)&out[32768 + (size_t)(bbase + b) * 1024 + 512 + jbase + jq] = r;
          }
        }
      }
    }

    // ---- exchange: drain -> EARLY flag publish -> prefetch -> detect ----
    // Ring data is written and drained exclusively by wave 0, so the flag
    // publish needs only wave0's vmcnt(0) — not the barrier join.
    WAIT_VM0();
    if (tid == 0 && active)   // l0 publishes p+1 slots, l1 publishes p
      __hip_atomic_store(Fown, (u32)(layer ? p : (p + 1)),
                         __ATOMIC_RELAXED, __HIP_MEMORY_SCOPE_AGENT);
    __syncthreads();
    const int np = p + 1;
    if (layer == 0 && np <= plast) {
      #pragma unroll
      for (int i = 0; i < 4; ++i) {
        const int u = tid + NTHR * i;
        const int r = u >> 7, c = (u & 127) * 4;
        const int tok = x[(bbase + r) * SEQ + np];
        pf[i] = *(const float4*)&emb[(size_t)tok * HID + c];
      }
    }
    if (np <= P) {
      if (tid < 64) {
        u32* fp  = Fown;            // dummy for idle lanes (always valid)
        u32  tgt = 0;
        bool ok  = true;            // idle lanes start satisfied
        if (lane < 16) { fp = F0 + lane * 32; tgt = (u32)np; ok = false; }
        else if (lane < 32) {
          if (layer) { fp = F1 + (lane - 16) * 32; tgt = (u32)(np - 1); ok = false; }
          else {
            const int th = np + 1 - ring;   // small-ring WAR throttle
            if (th > 0) { fp = F1 + (lane - 16) * 32; tgt = (u32)th; ok = false; }
          }
        }
        // latched poll: a lane stops loading once its peer passed; backoff
        // on failed ballot keeps straggler-poll traffic off the fabric.
        while (true) {
          if (!ok) ok = (__hip_atomic_load(fp, __ATOMIC_RELAXED,
                                           __HIP_MEMORY_SCOPE_AGENT) >= tgt);
          if (__ballot(ok) == ~0ull) break;
          __builtin_amdgcn_s_sleep(1);
        }
      }
      __syncthreads();
    }
    prev = cur; cur = wr0;
  }
}

extern "C" void kernel_launch(void* const* d_in, const int* in_sizes, int n_in,
                              void* d_out, int out_size, void* d_ws, size_t ws_size,
                              hipStream_t stream) {
  (void)in_sizes; (void)n_in; (void)out_size;
  const int*   x       = (const int*)d_in[0];
  const int*   lengths = (const int*)d_in[1];
  const float* emb     = (const float*)d_in[2];
  const float* W_ih    = (const float*)d_in[3];
  const float* W_hh    = (const float*)d_in[4];
  const float* b_ih    = (const float*)d_in[5];
  const float* b_hh    = (const float*)d_in[6];
  float* out = (float*)d_out;

  const size_t slotB = (size_t)SLOT * sizeof(float);            // 128KB
  const size_t needFull = 2 * (size_t)513 * slotB + 65536;      // ~131.5MB
  const int ring = (ws_size >= needFull) ? 513 : 17;            // 17: throttled

  float* h0r = (float*)d_ws;
  float* h1r = h0r + (size_t)ring * SLOT;
  u32*   F   = (u32*)(h1r + (size_t)ring * SLOT);

  // zero slot 0 of each ring (h(-1)=0) + flag page; ws re-poisoned each call
  hipMemsetAsync(h0r, 0, slotB, stream);
  hipMemsetAsync(h1r, 0, slotB, stream);
  hipMemsetAsync(F, 0, 32768, stream);

  hipLaunchKernelGGL(rnn_persistent, dim3(256), dim3(NTHR), 0, stream,
                     x, lengths, emb, W_ih, W_hh, b_ih, b_hh, out,
                     h0r, h1r, F, ring);
}